// Round 3
// baseline (488.336 us; speedup 1.0000x reference)
//
#include <hip/hip_runtime.h>
#include <hip/hip_bf16.h>

#define NB 4
#define NH 16
#define NS 2048
#define ND 64
#define QBLK 128
#define KVBLK 64
#define NT (NS / KVBLK)
#define VSTRIDE 144   // bytes; odd multiple of 16 -> bank-even b128 reads
#define PSTRIDE 144
#define NEG_MIN -3.4028234663852886e38f
#define LOG2E 1.44269504088896340736f

typedef __attribute__((ext_vector_type(4))) float f32x4;
typedef __attribute__((ext_vector_type(8))) short bf16x8;
typedef __attribute__((ext_vector_type(4))) __bf16 bf16v4;
typedef __attribute__((ext_vector_type(8))) __bf16 bf16v8;

__global__ __launch_bounds__(256, 4) void sdpa_fwd_kernel(
    const float* __restrict__ Qg, const float* __restrict__ Kg,
    const float* __restrict__ Vg, const float* __restrict__ Mg,
    float* __restrict__ Og)
{
    const int tid  = threadIdx.x;
    const int lane = tid & 63;
    const int wid  = tid >> 6;      // wave 0..3
    const int g    = lane >> 4;     // 0..3
    const int c    = lane & 15;     // 0..15

    // XCD-aware swizzle (bijective: 1024 % 8 == 0): XCD k owns heads [k*8, k*8+8)
    // so all 16 q-tile blocks of a head hit the same per-XCD L2.
    const int flat = (int)(blockIdx.x + blockIdx.y * gridDim.x);
    const int nf   = (flat & 7) * 128 + (flat >> 3);
    const int qt   = nf & 15;       // q tile (128 rows)
    const int bh   = nf >> 4;       // fused batch*head
    const int b    = bh >> 4;

    __shared__ char Kl[KVBLK * 128];          // 8 KB, bf16 row-major, XOR-swizzled
    __shared__ char Vl[ND * VSTRIDE];         // 9216 B, V^T [d][k] bf16
    __shared__ char Pl_all[4 * 32 * PSTRIDE]; // 18432 B, per-wave P
    __shared__ float biasl[KVBLK];
    char* Pw = Pl_all + wid * (32 * PSTRIDE);

    const long bh_base = (long)bh * NS * ND;

    // ---- Q fragments (B-operand: lane&15 = q, elems = k-dim), scale folded ----
    const float QSCALE = 0.125f * LOG2E;
    bf16x8 qfrag[2][2];
    #pragma unroll
    for (int s = 0; s < 2; ++s) {
        const float* qp = Qg + bh_base + (long)(qt * QBLK + wid * 32 + s * 16 + c) * ND;
        #pragma unroll
        for (int kk = 0; kk < 2; ++kk) {
            f32x4 f0 = *(const f32x4*)(qp + kk * 32 + g * 8);
            f32x4 f1 = *(const f32x4*)(qp + kk * 32 + g * 8 + 4);
            bf16v8 q;
            q[0] = (__bf16)(f0[0] * QSCALE); q[1] = (__bf16)(f0[1] * QSCALE);
            q[2] = (__bf16)(f0[2] * QSCALE); q[3] = (__bf16)(f0[3] * QSCALE);
            q[4] = (__bf16)(f1[0] * QSCALE); q[5] = (__bf16)(f1[1] * QSCALE);
            q[6] = (__bf16)(f1[2] * QSCALE); q[7] = (__bf16)(f1[3] * QSCALE);
            qfrag[s][kk] = *(bf16x8*)&q;
        }
    }

    float mrow[2] = {-1e30f, -1e30f};
    float lrow[2] = {0.0f, 0.0f};
    f32x4 oacc[2][4];
    #pragma unroll
    for (int s = 0; s < 2; ++s)
        #pragma unroll
        for (int dt = 0; dt < 4; ++dt) oacc[s][dt] = (f32x4){0.f, 0.f, 0.f, 0.f};

    // ---- async staging state (global -> regs early, regs -> LDS late) ----
    const int krow = tid >> 4, kc4 = tid & 15;   // K: 4 rows (krow+16i), 4 floats each
    const int dl   = lane;                        // V: lane owns column d=dl
    const float* vcol = Vg + bh_base + dl;
    f32x4 kreg[4];
    float vreg[16];
    float breg = 1.0f;

    auto issue_loads = [&](int kv0) {
        #pragma unroll
        for (int i = 0; i < 4; ++i)
            kreg[i] = *(const f32x4*)(Kg + bh_base + (long)(kv0 + krow + i * 16) * ND + kc4 * 4);
        #pragma unroll
        for (int i = 0; i < 4; ++i) {
            int k0 = (wid + i * 4) * 4;          // wave-disjoint k quads
            vreg[i * 4 + 0] = vcol[(long)(kv0 + k0 + 0) * ND];
            vreg[i * 4 + 1] = vcol[(long)(kv0 + k0 + 1) * ND];
            vreg[i * 4 + 2] = vcol[(long)(kv0 + k0 + 2) * ND];
            vreg[i * 4 + 3] = vcol[(long)(kv0 + k0 + 3) * ND];
        }
        if (tid < KVBLK) breg = Mg[(long)b * NS + kv0 + tid];
    };
    auto write_lds = [&]() {
        #pragma unroll
        for (int i = 0; i < 4; ++i) {
            bf16v4 h;
            h[0] = (__bf16)kreg[i][0]; h[1] = (__bf16)kreg[i][1];
            h[2] = (__bf16)kreg[i][2]; h[3] = (__bf16)kreg[i][3];
            int row = krow + i * 16;
            *(bf16v4*)(Kl + ((row * 128 + kc4 * 8) ^ ((row & 7) << 4))) = h;
        }
        #pragma unroll
        for (int i = 0; i < 4; ++i) {
            int k0 = (wid + i * 4) * 4;
            bf16v4 h;
            h[0] = (__bf16)vreg[i * 4 + 0]; h[1] = (__bf16)vreg[i * 4 + 1];
            h[2] = (__bf16)vreg[i * 4 + 2]; h[3] = (__bf16)vreg[i * 4 + 3];
            *(bf16v4*)(Vl + dl * VSTRIDE + k0 * 2) = h;
        }
        if (tid < KVBLK) biasl[tid] = (1.0f - breg) * NEG_MIN * LOG2E;
    };

    issue_loads(0);
    write_lds();

    for (int it = 0; it < NT; ++it) {
        __syncthreads();                          // LDS tile `it` visible
        if (it + 1 < NT) {
            issue_loads((it + 1) * KVBLK);        // in flight across the compute phase
            __builtin_amdgcn_sched_barrier(0);    // pin load issue before compute
        }

        // ---- S^T = K Q^T : lane holds S[key=t*16+g*4+r][q=c] ----
        f32x4 st[2][4];
        #pragma unroll
        for (int t = 0; t < 4; ++t) {
            int key = t * 16 + c;
            int sw = (key & 7) << 4;
            bf16x8 kb0 = *(const bf16x8*)(Kl + ((key * 128 + g * 16) ^ sw));
            bf16x8 kb1 = *(const bf16x8*)(Kl + ((key * 128 + 64 + g * 16) ^ sw));
            f32x4 bias4 = *(const f32x4*)(biasl + t * 16 + g * 4);
            #pragma unroll
            for (int s = 0; s < 2; ++s) {
                f32x4 acc = (f32x4){0.f, 0.f, 0.f, 0.f};
                acc = __builtin_amdgcn_mfma_f32_16x16x32_bf16(kb0, qfrag[s][0], acc, 0, 0, 0);
                acc = __builtin_amdgcn_mfma_f32_16x16x32_bf16(kb1, qfrag[s][1], acc, 0, 0, 0);
                st[s][t] = acc + bias4;
            }
        }

        // ---- online softmax with defer-max (THR=8) ----
        #pragma unroll
        for (int s = 0; s < 2; ++s) {
            float tm = st[s][0][0];
            #pragma unroll
            for (int t = 0; t < 4; ++t)
                #pragma unroll
                for (int r = 0; r < 4; ++r) tm = fmaxf(tm, st[s][t][r]);
            tm = fmaxf(tm, __shfl_xor(tm, 16));
            tm = fmaxf(tm, __shfl_xor(tm, 32));
            if (!__all(tm <= mrow[s] + 8.0f)) {   // rare: max grew, rescale O
                float mnew = fmaxf(mrow[s], tm);
                float scl = __builtin_amdgcn_exp2f(mrow[s] - mnew);
                mrow[s] = mnew;
                lrow[s] *= scl;
                #pragma unroll
                for (int r = 0; r < 4; ++r) {
                    float sb = __shfl(scl, g * 4 + r);
                    #pragma unroll
                    for (int dt = 0; dt < 4; ++dt) oacc[s][dt][r] *= sb;
                }
            }
            float ps = 0.f;
            #pragma unroll
            for (int t = 0; t < 4; ++t) {
                bf16v4 pb;
                #pragma unroll
                for (int r = 0; r < 4; ++r) {
                    float p = __builtin_amdgcn_exp2f(st[s][t][r] - mrow[s]);
                    ps += p;
                    pb[r] = (__bf16)p;
                }
                *(bf16v4*)(Pw + (s * 16 + c) * PSTRIDE + (t * 16 + g * 4) * 2) = pb;
            }
            ps += __shfl_xor(ps, 16);
            ps += __shfl_xor(ps, 32);
            lrow[s] += ps;
        }

        // wave-internal LDS write->read fence (P is per-wave)
        asm volatile("s_waitcnt lgkmcnt(0)" ::: "memory");
        __builtin_amdgcn_sched_barrier(0);

        // ---- O += P V ----
        bf16x8 pa[2][2];
        #pragma unroll
        for (int s = 0; s < 2; ++s)
            #pragma unroll
            for (int h = 0; h < 2; ++h)
                pa[s][h] = *(const bf16x8*)(Pw + (s * 16 + c) * PSTRIDE + h * 64 + g * 16);
        #pragma unroll
        for (int dt = 0; dt < 4; ++dt) {
            int d = dt * 16 + c;
            bf16x8 vb0 = *(const bf16x8*)(Vl + d * VSTRIDE + g * 16);
            bf16x8 vb1 = *(const bf16x8*)(Vl + d * VSTRIDE + 64 + g * 16);
            #pragma unroll
            for (int s = 0; s < 2; ++s) {
                oacc[s][dt] = __builtin_amdgcn_mfma_f32_16x16x32_bf16(pa[s][0], vb0, oacc[s][dt], 0, 0, 0);
                oacc[s][dt] = __builtin_amdgcn_mfma_f32_16x16x32_bf16(pa[s][1], vb1, oacc[s][dt], 0, 0, 0);
            }
        }

        __syncthreads();                          // all waves done reading LDS
        if (it + 1 < NT) write_lds();             // stage tile it+1 (regs -> LDS)
    }

    // ---- epilogue: normalize and store ----
    #pragma unroll
    for (int s = 0; s < 2; ++s) {
        float inv = 1.0f / lrow[s];
        #pragma unroll
        for (int r = 0; r < 4; ++r) {
            float ib = __shfl(inv, g * 4 + r);
            float* op = Og + bh_base + (long)(qt * QBLK + wid * 32 + s * 16 + g * 4 + r) * ND;
            #pragma unroll
            for (int dt = 0; dt < 4; ++dt)
                op[dt * 16 + c] = oacc[s][dt][r] * ib;
        }
    }
}

extern "C" void kernel_launch(void* const* d_in, const int* in_sizes, int n_in,
                              void* d_out, int out_size, void* d_ws, size_t ws_size,
                              hipStream_t stream) {
    const float* Q = (const float*)d_in[0];
    const float* K = (const float*)d_in[1];
    const float* V = (const float*)d_in[2];
    const float* M = (const float*)d_in[3];
    float* O = (float*)d_out;

    dim3 grid(NS / QBLK, NB * NH);   // 16 x 64 = 1024 blocks
    dim3 block(256);
    sdpa_fwd_kernel<<<grid, block, 0, stream>>>(Q, K, V, M, O);
}